// Round 7
// baseline (203.957 us; speedup 1.0000x reference)
//
#include <hip/hip_runtime.h>

#define BB 8
#define CC 64
#define NN 4096
#define JCH 8            // j-chunks in stats pass
#define LOG2E 1.4426950408889634f

typedef float f32x4  __attribute__((ext_vector_type(4)));
typedef float f32x16 __attribute__((ext_vector_type(16)));
typedef _Float16 half8_t __attribute__((ext_vector_type(8)));
typedef _Float16 half4_t __attribute__((ext_vector_type(4)));
typedef _Float16 half2_t __attribute__((ext_vector_type(2)));

typedef union { half8_t v8; half2_t v2[4]; } h8u;

// 32x32x16 f16 MFMA layouts (gfx950):
//   A[m][k]: m = lane&31, k = (lane>>5)*8 + j   (8 halves)
//   B[k][n]: n = lane&31, k = (lane>>5)*8 + j
//   C/D:     col = lane&31, row = (reg&3) + 8*(reg>>2) + 4*(lane>>5)

// ---------------------------------------------------------------------------
// Kernel A: 1x1-conv QKV. grid (12, NN/64, B), block 64.
// blockIdx.x encodes (z, oz): z = x>>2 selects {f,g,h}; oz = x&3 selects the
// 16-output slice — 4-way o-split for 4x the wave count (latency hiding).
// z=0 -> fT[b][n][c] (scaled by log2e), z=1 -> gT[b][n][c]   (straight rows)
// z=2 -> hT tiled: hT[b][n>>5][c][n&31]  (so attn stages h contiguously)
// ---------------------------------------------------------------------------
__global__ __launch_bounds__(64) void qkv_kernel(
    const float* __restrict__ x,
    const float* __restrict__ Wf, const float* __restrict__ bf,
    const float* __restrict__ Wg, const float* __restrict__ bg,
    const float* __restrict__ Wh, const float* __restrict__ bh,
    _Float16* __restrict__ fT, _Float16* __restrict__ gT,
    _Float16* __restrict__ hT)
{
    const int split = blockIdx.x;      // 0..11
    const int z     = split >> 2;
    const int o0    = (split & 3) * 16;
    const int n     = blockIdx.y * 64 + threadIdx.x;
    const int b     = blockIdx.z;
    const float* W    = (z == 0) ? Wf : ((z == 1) ? Wg : Wh);
    const float* bias = (z == 0) ? bf : ((z == 1) ? bg : bh);

    float xv[CC];
    const float* xp = x + (size_t)b * CC * NN + n;
#pragma unroll
    for (int c = 0; c < CC; ++c) xv[c] = xp[(size_t)c * NN];

    if (z < 2) {
        _Float16* dst = ((z == 0) ? fT : gT) + (size_t)(b * NN + n) * CC + o0;
        const float scale = (z == 0) ? LOG2E : 1.0f;
#pragma unroll
        for (int o8 = 0; o8 < 2; ++o8) {
            half8_t v;
#pragma unroll
            for (int oo = 0; oo < 8; ++oo) {
                const int o = o0 + o8 * 8 + oo;
                float acc = bias[o];
#pragma unroll
                for (int c = 0; c < CC; ++c) acc += W[o * CC + c] * xv[c];
                v[oo] = (_Float16)(acc * scale);
            }
            *(half8_t*)(dst + o8 * 8) = v;
        }
    } else {
        _Float16* hdst = hT + ((size_t)(b * (NN / 32) + (n >> 5)) * CC) * 32 + (n & 31);
#pragma unroll
        for (int o = o0; o < o0 + 16; ++o) {
            float acc = bias[o];
#pragma unroll
            for (int c = 0; c < CC; ++c) acc += W[o * CC + c] * xv[c];
            hdst[o * 32] = (_Float16)acc;
        }
    }
}

// ---------------------------------------------------------------------------
// Kernel B: partial row sums of exp2(logits). grid (NN/128, B, JCH), block 256.
// Wave owns i-tile 32; f A-frags entirely in registers. g streamed 64-j tiles
// through double-buffered LDS. 32x32x16 MFMA.
// ---------------------------------------------------------------------------
__global__ __launch_bounds__(256, 4) void stats_kernel(
    const _Float16* __restrict__ fT, const _Float16* __restrict__ gT,
    float* __restrict__ lpart)
{
    __shared__ _Float16 gbuf[2][64][72];   // stride 72 halves

    const int lane = threadIdx.x & 63;
    const int wv   = threadIdx.x >> 6;
    const int b    = blockIdx.y;
    const int jc   = blockIdx.z;
    const int i0   = blockIdx.x * 128 + wv * 32;
    const int l31  = lane & 31;
    const int q5   = lane >> 5;

    // A-frags (f rows i0..i0+31, K=64 in 4 chunks) — fixed in registers
    half8_t a[4];
    const _Float16* fa = fT + (size_t)(b * NN + i0 + l31) * CC + q5 * 8;
#pragma unroll
    for (int kc = 0; kc < 4; ++kc) a[kc] = *(const half8_t*)(fa + kc * 16);

    const _Float16* gchunk = gT + (size_t)(b * NN + jc * (NN / JCH)) * CC;
    const int T = NN / JCH / 64;   // 8 tiles of 64 j

    const int srow = wv * 16 + (lane >> 3);
    const int scol = (lane & 7) * 8;

    {   // stage tile 0
        const half8_t v0 = *(const half8_t*)(gchunk + (size_t)srow * CC + scol);
        const half8_t v1 = *(const half8_t*)(gchunk + (size_t)(srow + 8) * CC + scol);
        *(half8_t*)&gbuf[0][srow][scol] = v0;
        *(half8_t*)&gbuf[0][srow + 8][scol] = v1;
    }
    __syncthreads();

    float l16[16];
#pragma unroll
    for (int r = 0; r < 16; ++r) l16[r] = 0.f;

    for (int t = 0; t < T; ++t) {
        const int buf = t & 1;
        const bool pf = (t + 1 < T);
        half8_t p0, p1;
        if (pf) {
            const _Float16* src = gchunk + (size_t)((t + 1) * 64 + srow) * CC + scol;
            p0 = *(const half8_t*)(src);
            p1 = *(const half8_t*)(src + 8 * CC);
        }
#pragma unroll
        for (int js = 0; js < 2; ++js) {
            const _Float16* grow = &gbuf[buf][js * 32 + l31][0] + q5 * 8;
            f32x16 s = {};
#pragma unroll
            for (int kc = 0; kc < 4; ++kc) {
                const half8_t bfr = *(const half8_t*)(grow + kc * 16);
                s = __builtin_amdgcn_mfma_f32_32x32x16_f16(a[kc], bfr, s, 0, 0, 0);
            }
#pragma unroll
            for (int r = 0; r < 16; ++r) l16[r] += __builtin_exp2f(s[r]);
        }
        if (pf) {
            *(half8_t*)&gbuf[buf ^ 1][srow][scol] = p0;
            *(half8_t*)&gbuf[buf ^ 1][srow + 8][scol] = p1;
        }
        __syncthreads();
    }

    // reduce across the 32 j-columns (lanes sharing q5)
#pragma unroll
    for (int r = 0; r < 16; ++r) {
#pragma unroll
        for (int off = 1; off < 32; off <<= 1)
            l16[r] += __shfl_xor(l16[r], off);
    }

    if (l31 == 0) {
        float* lp = lpart + (size_t)jc * BB * NN + b * NN + i0;
#pragma unroll
        for (int rb = 0; rb < 4; ++rb) {
            // regs rb*4..rb*4+3 -> rows 8*rb + 4*q5 + 0..3
            f32x4 v;
#pragma unroll
            for (int k = 0; k < 4; ++k) v[k] = l16[rb * 4 + k];
            *(f32x4*)(lp + rb * 8 + q5 * 4) = v;
        }
    }
}

// ---------------------------------------------------------------------------
// Kernel B2: nbias = -log2(sum_jc lpart)  (softmax normalizer, log2 domain)
// ---------------------------------------------------------------------------
__global__ __launch_bounds__(256) void rmerge_kernel(
    const float* __restrict__ lpart, float* __restrict__ nbias)
{
    const int idx = blockIdx.x * 256 + threadIdx.x;
    float s = 0.f;
#pragma unroll
    for (int jc = 0; jc < JCH; ++jc) s += lpart[(size_t)jc * BB * NN + idx];
    nbias[idx] = -__builtin_log2f(s);
}

// ---------------------------------------------------------------------------
// Kernel C: partial out chunks. grid (NN/128, B, NIC), block 256.
// NIC = gridDim.z (4 or 8, chosen by ws budget). Wave owns j-tile 32 (g
// B-frags in registers); streams i in tiles of 32 through double-buffered LDS.
// P's C-layout -> B-layout transform is done IN-REGISTER via shfl_xor(32)
// (lanes j,q5=0 <-> j,q5=1 exchange half2-packed values) — no LDS round-trip.
// Normalizer folded into S-MFMA C-init: P = exp2(s + nbias) in (0,1].
// ---------------------------------------------------------------------------
__global__ __launch_bounds__(256, 4) void attn_kernel(
    const _Float16* __restrict__ fT, const _Float16* __restrict__ gT,
    const _Float16* __restrict__ hT, const float* __restrict__ nbias,
    _Float16* __restrict__ pout)
{
    __shared__ _Float16 fbuf[2][32][72];   // 9.0 KB  (i rows, 64 c + pad)
    __shared__ _Float16 hbuf[2][64][40];   // 10 KB   (c rows, 32 i + pad)

    const int lane = threadIdx.x & 63;
    const int wv   = threadIdx.x >> 6;
    const int b    = blockIdx.y;
    const int ic   = blockIdx.z;
    const int nic  = gridDim.z;
    const int l31  = lane & 31;
    const int q5   = lane >> 5;
    const int j    = blockIdx.x * 128 + wv * 32 + l31;

    // g B-frags fixed per wave: B[k=c][n=j], 4 K-chunks
    half8_t bg[4];
    const _Float16* grow = gT + (size_t)(b * NN + j) * CC + q5 * 8;
#pragma unroll
    for (int kc = 0; kc < 4; ++kc) bg[kc] = *(const half8_t*)(grow + kc * 16);

    f32x16 acc[2] = {};   // c 0..31, 32..63

    const int ichunk = NN / nic;
    const int ibase  = ic * ichunk;
    const _Float16* fchunk = fT + ((size_t)b * NN + ibase) * CC;
    const _Float16* htile0 = hT + ((size_t)(b * (NN / 32) + ibase / 32) * CC) * 32;
    const float*    nb     = nbias + b * NN + ibase;
    const int T = ichunk / 32;

    // staging maps (256 threads cover each 4 KB tile)
    const int tid    = threadIdx.x;
    const int frow_s = tid >> 3;            // 0..31
    const int fcol_s = (tid & 7) * 8;
    const int hoff_s = tid * 8;             // contiguous within 2048-half h tile
    const int hrow_s = tid >> 2;            // 0..63
    const int hcol_s = (tid & 3) * 8;

    {   // stage tile 0
        const half8_t fv = *(const half8_t*)(fchunk + (size_t)frow_s * CC + fcol_s);
        const half8_t hv = *(const half8_t*)(htile0 + hoff_s);
        *(half8_t*)&fbuf[0][frow_s][fcol_s] = fv;
        *(half8_t*)&hbuf[0][hrow_s][hcol_s] = hv;
    }
    __syncthreads();

    for (int t = 0; t < T; ++t) {
        const int buf = t & 1;
        const bool pf = (t + 1 < T);
        half8_t pfv, phv;
        if (pf) {
            pfv = *(const half8_t*)(fchunk + (size_t)((t + 1) * 32 + frow_s) * CC + fcol_s);
            phv = *(const half8_t*)(htile0 + (size_t)(t + 1) * CC * 32 + hoff_s);
        }

        // ---- S = f . g^T + nbias ----
        f32x16 s;
        {   // C-init: s[reg r] -> row (r&3)+8*(r>>2)+4*q5
#pragma unroll
            for (int rb = 0; rb < 4; ++rb) {
                const f32x4 n4 = *(const f32x4*)(nb + t * 32 + rb * 8 + q5 * 4);
#pragma unroll
                for (int k = 0; k < 4; ++k) s[rb * 4 + k] = n4[k];
            }
        }
        const _Float16* frow = &fbuf[buf][l31][0] + q5 * 8;
#pragma unroll
        for (int kc = 0; kc < 4; ++kc) {
            const half8_t af = *(const half8_t*)(frow + kc * 16);
            s = __builtin_amdgcn_mfma_f32_32x32x16_f16(af, bg[kc], s, 0, 0, 0);
        }

        // ---- P = exp2(s), packed half2 per reg-pair ----
        // P[r8] holds rows (i_local) for regs 2*r8, 2*r8+1 of THIS lane.
        half2_t P[8];
#pragma unroll
        for (int r8 = 0; r8 < 8; ++r8) {
            half2_t v;
            v[0] = (_Float16)__builtin_exp2f(s[r8 * 2]);
            v[1] = (_Float16)__builtin_exp2f(s[r8 * 2 + 1]);
            P[r8] = v;
        }

        // ---- C-layout -> B-layout via xor-32 lane exchange ----
        // q5=0 lane owns i {0-3,8-11,16-19,24-27}; q5=1 owns {4-7,12-15,20-23,28-31}.
        // q5=0 needs partner's P0,P1 (i4-7) and P4,P5 (i20-23);
        // q5=1 needs partner's P2,P3 (i8-11) and P6,P7 (i24-27).
        const int sA = __builtin_bit_cast(int, q5 ? P[0] : P[2]);
        const int sB = __builtin_bit_cast(int, q5 ? P[1] : P[3]);
        const int sC = __builtin_bit_cast(int, q5 ? P[4] : P[6]);
        const int sD = __builtin_bit_cast(int, q5 ? P[5] : P[7]);
        const half2_t rA = __builtin_bit_cast(half2_t, __shfl_xor(sA, 32, 64));
        const half2_t rB = __builtin_bit_cast(half2_t, __shfl_xor(sB, 32, 64));
        const half2_t rC = __builtin_bit_cast(half2_t, __shfl_xor(sC, 32, 64));
        const half2_t rD = __builtin_bit_cast(half2_t, __shfl_xor(sD, 32, 64));

        h8u B0, B1;   // B-frags: k = q5*8 + jj; B0 covers i 0..15, B1 i 16..31
        B0.v2[0] = q5 ? rA   : P[0];
        B0.v2[1] = q5 ? rB   : P[1];
        B0.v2[2] = q5 ? P[2] : rA;
        B0.v2[3] = q5 ? P[3] : rB;
        B1.v2[0] = q5 ? rC   : P[4];
        B1.v2[1] = q5 ? rD   : P[5];
        B1.v2[2] = q5 ? P[6] : rC;
        B1.v2[3] = q5 ? P[7] : rD;

        // ---- PV: acc[ct] += h[ct*32+..][i] . P[i][j] ----
#pragma unroll
        for (int ct = 0; ct < 2; ++ct) {
            const half8_t ah0 = *(const half8_t*)(&hbuf[buf][ct * 32 + l31][0] + q5 * 8);
            acc[ct] = __builtin_amdgcn_mfma_f32_32x32x16_f16(ah0, B0.v8, acc[ct], 0, 0, 0);
        }
#pragma unroll
        for (int ct = 0; ct < 2; ++ct) {
            const half8_t ah1 = *(const half8_t*)(&hbuf[buf][ct * 32 + l31][0] + 16 + q5 * 8);
            acc[ct] = __builtin_amdgcn_mfma_f32_32x32x16_f16(ah1, B1.v8, acc[ct], 0, 0, 0);
        }

        if (pf) {
            *(half8_t*)&fbuf[buf ^ 1][frow_s][fcol_s] = pfv;
            *(half8_t*)&hbuf[buf ^ 1][hrow_s][hcol_s] = phv;
        }
        __syncthreads();
    }

    // epilogue: pout[ic][b][c][j]; c = ct*32 + (r&3)+8*(r>>2)+4*q5
    _Float16* pb_out = pout + (((size_t)ic * BB + b) * CC) * NN;
#pragma unroll
    for (int ct = 0; ct < 2; ++ct) {
#pragma unroll
        for (int r = 0; r < 16; ++r) {
            const int c = ct * 32 + (r & 3) + 8 * (r >> 2) + 4 * q5;
            pb_out[(size_t)c * NN + j] = (_Float16)acc[ct][r];
        }
    }
}

// ---------------------------------------------------------------------------
// Kernel D: out = gamma * sum_ic pout[ic] + x.  8 elems/thread, vectorized.
// ---------------------------------------------------------------------------
__global__ __launch_bounds__(256) void combine_kernel(
    const float* __restrict__ x, const float* __restrict__ gammap,
    const _Float16* __restrict__ pout, float* __restrict__ out, int nic)
{
    const float gam = gammap[0];
    const size_t i8 = ((size_t)blockIdx.x * 256 + threadIdx.x) * 8;
    const size_t TOT = (size_t)BB * CC * NN;

    float s[8] = {0.f, 0.f, 0.f, 0.f, 0.f, 0.f, 0.f, 0.f};
    for (int ic = 0; ic < nic; ++ic) {
        const half8_t p = *(const half8_t*)(pout + ic * TOT + i8);
#pragma unroll
        for (int k = 0; k < 8; ++k) s[k] += (float)p[k];
    }
    const f32x4 x0 = *(const f32x4*)(x + i8);
    const f32x4 x1 = *(const f32x4*)(x + i8 + 4);
    f32x4 o0, o1;
#pragma unroll
    for (int k = 0; k < 4; ++k) { o0[k] = gam * s[k] + x0[k]; o1[k] = gam * s[k + 4] + x1[k]; }
    *(f32x4*)(out + i8) = o0;
    *(f32x4*)(out + i8 + 4) = o1;
}

// ---------------------------------------------------------------------------
extern "C" void kernel_launch(void* const* d_in, const int* in_sizes, int n_in,
                              void* d_out, int out_size, void* d_ws, size_t ws_size,
                              hipStream_t stream) {
    const float* x     = (const float*)d_in[0];
    const float* Wf    = (const float*)d_in[1];
    const float* bf    = (const float*)d_in[2];
    const float* Wg    = (const float*)d_in[3];
    const float* bg    = (const float*)d_in[4];
    const float* Wh    = (const float*)d_in[5];
    const float* bh    = (const float*)d_in[6];
    const float* gamma = (const float*)d_in[7];
    float* out = (float*)d_out;

    const size_t TOT = (size_t)BB * CC * NN;        // 2M elems
    // ws budget: 3 f16 tensors (12 MB) + pout (nic*4 MB) + lpart (1 MB) + nbias (128 KB)
    const size_t fixed = 3 * TOT * 2 + (size_t)JCH * BB * NN * 4 + (size_t)BB * NN * 4;
    const int nic = (ws_size >= fixed + 8 * TOT * 2) ? 8 : 4;

    _Float16* fT   = (_Float16*)d_ws;               // 4 MB
    _Float16* gT   = fT + TOT;                      // 4 MB
    _Float16* hT   = gT + TOT;                      // 4 MB
    _Float16* pout = hT + TOT;                      // nic * 4 MB
    float* lpart   = (float*)(pout + (size_t)nic * TOT);  // 1 MB
    float* nbias   = lpart + (size_t)JCH * BB * NN;       // 128 KB

    qkv_kernel<<<dim3(12, NN / 64, BB), 64, 0, stream>>>(
        x, Wf, bf, Wg, bg, Wh, bh, fT, gT, hT);
    stats_kernel<<<dim3(NN / 128, BB, JCH), 256, 0, stream>>>(fT, gT, lpart);
    rmerge_kernel<<<dim3(BB * NN / 256), 256, 0, stream>>>(lpart, nbias);
    attn_kernel<<<dim3(NN / 128, BB, nic), 256, 0, stream>>>(fT, gT, hT, nbias, pout);
    combine_kernel<<<dim3(TOT / (256 * 8)), 256, 0, stream>>>(x, gamma, pout, out, nic);
}

// Round 9
// 199.967 us; speedup vs baseline: 1.0200x; 1.0200x over previous
//
#include <hip/hip_runtime.h>

#define BB 8
#define CC 64
#define NN 4096
#define NIC 4            // i-chunks in attn pass
#define JCH 8            // j-chunks in stats pass
#define LOG2E 1.4426950408889634f

typedef float f32x4  __attribute__((ext_vector_type(4)));
typedef float f32x16 __attribute__((ext_vector_type(16)));
typedef _Float16 half8_t __attribute__((ext_vector_type(8)));
typedef int int4v __attribute__((ext_vector_type(4)));

// 32x32x16 f16 MFMA layouts (gfx950):
//   A[m][k]: m = lane&31, k = (lane>>5)*8 + idx   (8 halves)
//   B[k][n]: n = lane&31, k = (lane>>5)*8 + idx
//   C/D:     col = lane&31, row = (reg&3) + 8*(reg>>2) + 4*(lane>>5)

// ---------------------------------------------------------------------------
// Kernel A: 1x1-conv QKV. grid (12, NN/64, B), block 64.
// blockIdx.x encodes (z, oz): z = x>>2 selects {f,g,h}; oz = x&3 selects the
// 16-output slice — 4-way o-split for 4x the wave count (latency hiding).
// z=0 -> fT[b][n][c] (scaled by log2e), z=1 -> gT[b][n][c]   (straight rows)
// z=2 -> hT tiled: hT[b][n>>5][c][n&31]  (so attn stages h contiguously)
// ---------------------------------------------------------------------------
__global__ __launch_bounds__(64) void qkv_kernel(
    const float* __restrict__ x,
    const float* __restrict__ Wf, const float* __restrict__ bf,
    const float* __restrict__ Wg, const float* __restrict__ bg,
    const float* __restrict__ Wh, const float* __restrict__ bh,
    _Float16* __restrict__ fT, _Float16* __restrict__ gT,
    _Float16* __restrict__ hT)
{
    const int split = blockIdx.x;      // 0..11
    const int z     = split >> 2;
    const int o0    = (split & 3) * 16;
    const int n     = blockIdx.y * 64 + threadIdx.x;
    const int b     = blockIdx.z;
    const float* W    = (z == 0) ? Wf : ((z == 1) ? Wg : Wh);
    const float* bias = (z == 0) ? bf : ((z == 1) ? bg : bh);

    float xv[CC];
    const float* xp = x + (size_t)b * CC * NN + n;
#pragma unroll
    for (int c = 0; c < CC; ++c) xv[c] = xp[(size_t)c * NN];

    if (z < 2) {
        _Float16* dst = ((z == 0) ? fT : gT) + (size_t)(b * NN + n) * CC + o0;
        const float scale = (z == 0) ? LOG2E : 1.0f;
#pragma unroll
        for (int o8 = 0; o8 < 2; ++o8) {
            half8_t v;
#pragma unroll
            for (int oo = 0; oo < 8; ++oo) {
                const int o = o0 + o8 * 8 + oo;
                float acc = bias[o];
#pragma unroll
                for (int c = 0; c < CC; ++c) acc += W[o * CC + c] * xv[c];
                v[oo] = (_Float16)(acc * scale);
            }
            *(half8_t*)(dst + o8 * 8) = v;
        }
    } else {
        _Float16* hdst = hT + ((size_t)(b * (NN / 32) + (n >> 5)) * CC) * 32 + (n & 31);
#pragma unroll
        for (int o = o0; o < o0 + 16; ++o) {
            float acc = bias[o];
#pragma unroll
            for (int c = 0; c < CC; ++c) acc += W[o * CC + c] * xv[c];
            hdst[o * 32] = (_Float16)acc;
        }
    }
}

// ---------------------------------------------------------------------------
// Kernel B: partial row sums of exp2(logits). grid (NN/128, B, JCH), block 256.
// Wave owns i-tile 32; f A-frags entirely in registers. g streamed 64-j tiles
// through double-buffered LDS. 32x32x16 MFMA.
// ---------------------------------------------------------------------------
__global__ __launch_bounds__(256, 4) void stats_kernel(
    const _Float16* __restrict__ fT, const _Float16* __restrict__ gT,
    float* __restrict__ lpart)
{
    __shared__ _Float16 gbuf[2][64][72];   // stride 72 halves

    const int lane = threadIdx.x & 63;
    const int wv   = threadIdx.x >> 6;
    const int b    = blockIdx.y;
    const int jc   = blockIdx.z;
    const int i0   = blockIdx.x * 128 + wv * 32;
    const int l31  = lane & 31;
    const int q5   = lane >> 5;

    // A-frags (f rows i0..i0+31, K=64 in 4 chunks) — fixed in registers
    half8_t a[4];
    const _Float16* fa = fT + (size_t)(b * NN + i0 + l31) * CC + q5 * 8;
#pragma unroll
    for (int kc = 0; kc < 4; ++kc) a[kc] = *(const half8_t*)(fa + kc * 16);

    const _Float16* gchunk = gT + (size_t)(b * NN + jc * (NN / JCH)) * CC;
    const int T = NN / JCH / 64;   // 8 tiles of 64 j

    const int srow = wv * 16 + (lane >> 3);
    const int scol = (lane & 7) * 8;

    {   // stage tile 0
        const half8_t v0 = *(const half8_t*)(gchunk + (size_t)srow * CC + scol);
        const half8_t v1 = *(const half8_t*)(gchunk + (size_t)(srow + 8) * CC + scol);
        *(half8_t*)&gbuf[0][srow][scol] = v0;
        *(half8_t*)&gbuf[0][srow + 8][scol] = v1;
    }
    __syncthreads();

    float l16[16];
#pragma unroll
    for (int r = 0; r < 16; ++r) l16[r] = 0.f;

    for (int t = 0; t < T; ++t) {
        const int buf = t & 1;
        const bool pf = (t + 1 < T);
        half8_t p0, p1;
        if (pf) {
            const _Float16* src = gchunk + (size_t)((t + 1) * 64 + srow) * CC + scol;
            p0 = *(const half8_t*)(src);
            p1 = *(const half8_t*)(src + 8 * CC);
        }
#pragma unroll
        for (int js = 0; js < 2; ++js) {
            const _Float16* grow = &gbuf[buf][js * 32 + l31][0] + q5 * 8;
            f32x16 s = {};
#pragma unroll
            for (int kc = 0; kc < 4; ++kc) {
                const half8_t bfr = *(const half8_t*)(grow + kc * 16);
                s = __builtin_amdgcn_mfma_f32_32x32x16_f16(a[kc], bfr, s, 0, 0, 0);
            }
#pragma unroll
            for (int r = 0; r < 16; ++r) l16[r] += __builtin_exp2f(s[r]);
        }
        if (pf) {
            *(half8_t*)&gbuf[buf ^ 1][srow][scol] = p0;
            *(half8_t*)&gbuf[buf ^ 1][srow + 8][scol] = p1;
        }
        __syncthreads();
    }

    // reduce across the 32 j-columns (lanes sharing q5)
#pragma unroll
    for (int r = 0; r < 16; ++r) {
#pragma unroll
        for (int off = 1; off < 32; off <<= 1)
            l16[r] += __shfl_xor(l16[r], off);
    }

    if (l31 == 0) {
        float* lp = lpart + (size_t)jc * BB * NN + b * NN + i0;
#pragma unroll
        for (int rb = 0; rb < 4; ++rb) {
            // regs rb*4..rb*4+3 -> rows 8*rb + 4*q5 + 0..3
            f32x4 v;
#pragma unroll
            for (int k = 0; k < 4; ++k) v[k] = l16[rb * 4 + k];
            *(f32x4*)(lp + rb * 8 + q5 * 4) = v;
        }
    }
}

// ---------------------------------------------------------------------------
// Kernel B2: nbias = -log2(sum_jc lpart)  (softmax normalizer, log2 domain)
// ---------------------------------------------------------------------------
__global__ __launch_bounds__(256) void rmerge_kernel(
    const float* __restrict__ lpart, float* __restrict__ nbias)
{
    const int idx = blockIdx.x * 256 + threadIdx.x;
    float s = 0.f;
#pragma unroll
    for (int jc = 0; jc < JCH; ++jc) s += lpart[(size_t)jc * BB * NN + idx];
    nbias[idx] = -__builtin_log2f(s);
}

// ---------------------------------------------------------------------------
// Kernel C: partial out chunks. grid (NN/128, B, NIC), block 256.
// Wave owns j-tile 32 (g B-frags in registers); streams i in tiles of 64
// (two 32-i halves per iteration) through double-buffered LDS, ONE barrier
// per 64-i tile. P's C->B layout transform in-register via shfl_xor(32).
// Normalizer folded into S-MFMA C-init: P = exp2(s + nbias) in (0,1].
// ---------------------------------------------------------------------------
__global__ __launch_bounds__(256, 4) void attn_kernel(
    const _Float16* __restrict__ fT, const _Float16* __restrict__ gT,
    const _Float16* __restrict__ hT, const float* __restrict__ nbias,
    _Float16* __restrict__ pout)
{
    __shared__ _Float16 fbuf[2][64][72];   // 18.4 KB (i rows, 64 c + pad)
    __shared__ _Float16 hbuf[2][64][72];   // 18.4 KB (c rows, 64 i + pad)

    const int lane = threadIdx.x & 63;
    const int wv   = threadIdx.x >> 6;
    const int b    = blockIdx.y;
    const int ic   = blockIdx.z;
    const int l31  = lane & 31;
    const int q5   = lane >> 5;
    const int j    = blockIdx.x * 128 + wv * 32 + l31;

    // g B-frags fixed per wave: B[k=c][n=j], 4 K-chunks
    half8_t bg[4];
    const _Float16* grow = gT + (size_t)(b * NN + j) * CC + q5 * 8;
#pragma unroll
    for (int kc = 0; kc < 4; ++kc) bg[kc] = *(const half8_t*)(grow + kc * 16);

    f32x16 acc[2] = {};   // c 0..31, 32..63

    const int ichunk = NN / NIC;           // 1024
    const int ibase  = ic * ichunk;
    const _Float16* fchunk = fT + ((size_t)b * NN + ibase) * CC;
    const _Float16* hchunk = hT + ((size_t)(b * (NN / 32) + ibase / 32) * CC) * 32;
    const float*    nb     = nbias + b * NN + ibase;
    const int T = ichunk / 64;             // 16 iterations

    // staging maps: 256 threads cover each 8 KB (64x64 half) tile
    const int tid    = threadIdx.x;
    const int frow_s = tid >> 2;            // 0..63
    const int fcol_s = (tid & 3) * 16;      // two half8 at +0,+8
    const int hrow_s = tid >> 2;            // c 0..63
    const int hcol_s = (tid & 3) * 8;       // i within 32-chunk

    {   // stage tile 0 (f: rows=i, cols=c; h: two 32-i subtiles)
        const half8_t f0 = *(const half8_t*)(fchunk + (size_t)frow_s * CC + fcol_s);
        const half8_t f1 = *(const half8_t*)(fchunk + (size_t)frow_s * CC + fcol_s + 8);
        const half8_t h0 = *(const half8_t*)(hchunk + tid * 8);
        const half8_t h1 = *(const half8_t*)(hchunk + 2048 + tid * 8);
        *(half8_t*)&fbuf[0][frow_s][fcol_s]     = f0;
        *(half8_t*)&fbuf[0][frow_s][fcol_s + 8] = f1;
        *(half8_t*)&hbuf[0][hrow_s][hcol_s]      = h0;
        *(half8_t*)&hbuf[0][hrow_s][32 + hcol_s] = h1;
    }
    __syncthreads();

    for (int t = 0; t < T; ++t) {
        const int buf = t & 1;
        const bool pf = (t + 1 < T);
        half8_t pf0, pf1, ph0, ph1;
        if (pf) {
            const _Float16* fsrc = fchunk + (size_t)((t + 1) * 64 + frow_s) * CC + fcol_s;
            const _Float16* hsrc = hchunk + (size_t)(t + 1) * 4096 + tid * 8;
            pf0 = *(const half8_t*)(fsrc);
            pf1 = *(const half8_t*)(fsrc + 8);
            ph0 = *(const half8_t*)(hsrc);
            ph1 = *(const half8_t*)(hsrc + 2048);
        }

#pragma unroll
        for (int ih = 0; ih < 2; ++ih) {
            // ---- S = f . g^T + nbias (C-init) ----
            f32x16 s;
#pragma unroll
            for (int rb = 0; rb < 4; ++rb) {
                const f32x4 n4 = *(const f32x4*)(nb + t * 64 + ih * 32 + rb * 8 + q5 * 4);
#pragma unroll
                for (int k = 0; k < 4; ++k) s[rb * 4 + k] = n4[k];
            }
            const _Float16* frow = &fbuf[buf][ih * 32 + l31][0] + q5 * 8;
#pragma unroll
            for (int kc = 0; kc < 4; ++kc) {
                const half8_t af = *(const half8_t*)(frow + kc * 16);
                s = __builtin_amdgcn_mfma_f32_32x32x16_f16(af, bg[kc], s, 0, 0, 0);
            }

            // ---- P = exp2(s), packed f16 pairs (int-carried) ----
            int e[8];
#pragma unroll
            for (int r8 = 0; r8 < 8; ++r8) {
                e[r8] = __builtin_bit_cast(int, __builtin_amdgcn_cvt_pkrtz(
                    __builtin_exp2f(s[r8 * 2]), __builtin_exp2f(s[r8 * 2 + 1])));
            }

            // ---- C-layout -> B-layout via xor-32 lane exchange ----
            // q5=0 owns i {0-3,8-11,16-19,24-27}; q5=1 owns {4-7,...}.
            const int sA = q5 ? e[0] : e[2];
            const int sB = q5 ? e[1] : e[3];
            const int sC = q5 ? e[4] : e[6];
            const int sD = q5 ? e[5] : e[7];
            const int rA = __shfl_xor(sA, 32, 64);
            const int rB = __shfl_xor(sB, 32, 64);
            const int rC = __shfl_xor(sC, 32, 64);
            const int rD = __shfl_xor(sD, 32, 64);
            int4v b0, b1;
            b0[0] = q5 ? rA   : e[0];
            b0[1] = q5 ? rB   : e[1];
            b0[2] = q5 ? e[2] : rA;
            b0[3] = q5 ? e[3] : rB;
            b1[0] = q5 ? rC   : e[4];
            b1[1] = q5 ? rD   : e[5];
            b1[2] = q5 ? e[6] : rC;
            b1[3] = q5 ? e[7] : rD;
            const half8_t B0 = __builtin_bit_cast(half8_t, b0);
            const half8_t B1 = __builtin_bit_cast(half8_t, b1);

            // ---- PV: acc[ct] += h[ct*32+..][i] . P[i][j] ----
#pragma unroll
            for (int ct = 0; ct < 2; ++ct) {
                const half8_t ah0 = *(const half8_t*)(&hbuf[buf][ct * 32 + l31][0] + ih * 32 + q5 * 8);
                acc[ct] = __builtin_amdgcn_mfma_f32_32x32x16_f16(ah0, B0, acc[ct], 0, 0, 0);
            }
#pragma unroll
            for (int ct = 0; ct < 2; ++ct) {
                const half8_t ah1 = *(const half8_t*)(&hbuf[buf][ct * 32 + l31][0] + ih * 32 + 16 + q5 * 8);
                acc[ct] = __builtin_amdgcn_mfma_f32_32x32x16_f16(ah1, B1, acc[ct], 0, 0, 0);
            }
        }

        if (pf) {
            *(half8_t*)&fbuf[buf ^ 1][frow_s][fcol_s]     = pf0;
            *(half8_t*)&fbuf[buf ^ 1][frow_s][fcol_s + 8] = pf1;
            *(half8_t*)&hbuf[buf ^ 1][hrow_s][hcol_s]      = ph0;
            *(half8_t*)&hbuf[buf ^ 1][hrow_s][32 + hcol_s] = ph1;
        }
        __syncthreads();
    }

    // epilogue: pout[ic][b][c][j]; c = ct*32 + (r&3)+8*(r>>2)+4*q5
    _Float16* pb_out = pout + (((size_t)ic * BB + b) * CC) * NN;
#pragma unroll
    for (int ct = 0; ct < 2; ++ct) {
#pragma unroll
        for (int r = 0; r < 16; ++r) {
            const int c = ct * 32 + (r & 3) + 8 * (r >> 2) + 4 * q5;
            pb_out[(size_t)c * NN + j] = (_Float16)acc[ct][r];
        }
    }
}

// ---------------------------------------------------------------------------
// Kernel D: out = gamma * sum_ic pout[ic] + x.  8 elems/thread, vectorized.
// ---------------------------------------------------------------------------
__global__ __launch_bounds__(256) void combine_kernel(
    const float* __restrict__ x, const float* __restrict__ gammap,
    const _Float16* __restrict__ pout, float* __restrict__ out)
{
    const float gam = gammap[0];
    const size_t i8 = ((size_t)blockIdx.x * 256 + threadIdx.x) * 8;
    const size_t TOT = (size_t)BB * CC * NN;

    float s[8] = {0.f, 0.f, 0.f, 0.f, 0.f, 0.f, 0.f, 0.f};
#pragma unroll
    for (int ic = 0; ic < NIC; ++ic) {
        const half8_t p = *(const half8_t*)(pout + ic * TOT + i8);
#pragma unroll
        for (int k = 0; k < 8; ++k) s[k] += (float)p[k];
    }
    const f32x4 x0 = *(const f32x4*)(x + i8);
    const f32x4 x1 = *(const f32x4*)(x + i8 + 4);
    f32x4 o0, o1;
#pragma unroll
    for (int k = 0; k < 4; ++k) { o0[k] = gam * s[k] + x0[k]; o1[k] = gam * s[k + 4] + x1[k]; }
    *(f32x4*)(out + i8) = o0;
    *(f32x4*)(out + i8 + 4) = o1;
}

// ---------------------------------------------------------------------------
extern "C" void kernel_launch(void* const* d_in, const int* in_sizes, int n_in,
                              void* d_out, int out_size, void* d_ws, size_t ws_size,
                              hipStream_t stream) {
    const float* x     = (const float*)d_in[0];
    const float* Wf    = (const float*)d_in[1];
    const float* bf    = (const float*)d_in[2];
    const float* Wg    = (const float*)d_in[3];
    const float* bg    = (const float*)d_in[4];
    const float* Wh    = (const float*)d_in[5];
    const float* bh    = (const float*)d_in[6];
    const float* gamma = (const float*)d_in[7];
    float* out = (float*)d_out;

    const size_t TOT = (size_t)BB * CC * NN;        // 2M elems
    _Float16* fT   = (_Float16*)d_ws;               // 4 MB
    _Float16* gT   = fT + TOT;                      // 4 MB
    _Float16* hT   = gT + TOT;                      // 4 MB
    _Float16* pout = hT + TOT;                      // NIC * 4 MB
    float* lpart   = (float*)(pout + (size_t)NIC * TOT);  // 1 MB
    float* nbias   = lpart + (size_t)JCH * BB * NN;       // 128 KB

    qkv_kernel<<<dim3(12, NN / 64, BB), 64, 0, stream>>>(
        x, Wf, bf, Wg, bg, Wh, bh, fT, gT, hT);
    stats_kernel<<<dim3(NN / 128, BB, JCH), 256, 0, stream>>>(fT, gT, lpart);
    rmerge_kernel<<<dim3(BB * NN / 256), 256, 0, stream>>>(lpart, nbias);
    attn_kernel<<<dim3(NN / 128, BB, NIC), 256, 0, stream>>>(fT, gT, hT, nbias, pout);
    combine_kernel<<<dim3(TOT / (256 * 8)), 256, 0, stream>>>(x, gamma, pout, out);
}

// Round 10
// 177.165 us; speedup vs baseline: 1.1512x; 1.1287x over previous
//
#include <hip/hip_runtime.h>

#define BB 8
#define CC 64
#define NN 4096
#define NIC 4            // i-chunks in attn pass
#define JCH 8            // j-chunks in stats pass
#define LOG2E 1.4426950408889634f

typedef float f32x4  __attribute__((ext_vector_type(4)));
typedef float f32x16 __attribute__((ext_vector_type(16)));
typedef _Float16 half8_t __attribute__((ext_vector_type(8)));
typedef int int4v __attribute__((ext_vector_type(4)));

// 32x32x16 f16 MFMA layouts (gfx950):
//   A[m][k]: m = lane&31, k = (lane>>5)*8 + idx   (8 halves)
//   B[k][n]: n = lane&31, k = (lane>>5)*8 + idx
//   C/D:     col = lane&31, row = (reg&3) + 8*(reg>>2) + 4*(lane>>5)
// NOTE: A and B fragment layouts are IDENTICAL — swapping operand order
// transposes which index (reg vs lane) carries M — exploited in qkv.

// ---------------------------------------------------------------------------
// Kernel A: 1x1-conv QKV via MFMA. grid (NN/128, B, 3), block 256 (4 waves).
// Block stages x fp32 tile [64 c][128 n] in LDS once; wave wv owns pixel
// sub-tile pt=wv (32 px) and computes all 64 outputs (2 o-tiles).
//   z<2 (f,g): D = mfma(xfrag, wfrag)  -> col=o    -> coalesced [n][c] store
//   z=2 (h):   D = mfma(wfrag, xfrag)  -> col=px   -> coalesced hT store
// z=0 -> fT[b][n][c] scaled by log2e; z=1 -> gT[b][n][c];
// z=2 -> hT[b][n>>5][c][n&31].
// ---------------------------------------------------------------------------
__global__ __launch_bounds__(256, 4) void qkv_kernel(
    const float* __restrict__ x,
    const float* __restrict__ Wf, const float* __restrict__ bf,
    const float* __restrict__ Wg, const float* __restrict__ bg,
    const float* __restrict__ Wh, const float* __restrict__ bh,
    _Float16* __restrict__ fT, _Float16* __restrict__ gT,
    _Float16* __restrict__ hT)
{
    __shared__ float xbuf[64][136];        // 34.8 KB, stride 136 floats

    const int tid  = threadIdx.x;
    const int lane = tid & 63;
    const int wv   = tid >> 6;
    const int l31  = lane & 31;
    const int q5   = lane >> 5;
    const int n0   = blockIdx.x * 128;
    const int b    = blockIdx.y;
    const int z    = blockIdx.z;
    const float* W    = (z == 0) ? Wf : ((z == 1) ? Wg : Wh);
    const float* bias = (z == 0) ? bf : ((z == 1) ? bg : bh);

    // ---- stage x tile: 64 rows x 128 floats, 8 f32x4 per thread ----
    {
        const int row = tid >> 2;                  // 0..63
        const float* src = x + (size_t)(b * CC + row) * NN + n0 + (tid & 3) * 4;
#pragma unroll
        for (int k = 0; k < 8; ++k) {
            const f32x4 v = *(const f32x4*)(src + k * 16);
            *(f32x4*)&xbuf[row][(tid & 3) * 4 + k * 16] = v;
        }
    }
    __syncthreads();

    // ---- x-frags for this wave's pixel tile (m/n = px = pt*32+l31) ----
    const int px = wv * 32 + l31;
    half8_t xf[4];
#pragma unroll
    for (int kc = 0; kc < 4; ++kc) {
        const int kb = kc * 16 + q5 * 8;
        int4v p;
#pragma unroll
        for (int h2 = 0; h2 < 4; ++h2) {
            p[h2] = __builtin_bit_cast(int, __builtin_amdgcn_cvt_pkrtz(
                xbuf[kb + h2 * 2][px], xbuf[kb + h2 * 2 + 1][px]));
        }
        xf[kc] = __builtin_bit_cast(half8_t, p);
    }

    // ---- W-frags for 2 o-tiles (m/n = o = ot*32+l31) ----
    half8_t wf[2][4];
#pragma unroll
    for (int ot = 0; ot < 2; ++ot) {
        const float* wrow = W + (size_t)(ot * 32 + l31) * CC;
#pragma unroll
        for (int kc = 0; kc < 4; ++kc) {
            const f32x4 w0 = *(const f32x4*)(wrow + kc * 16 + q5 * 8);
            const f32x4 w1 = *(const f32x4*)(wrow + kc * 16 + q5 * 8 + 4);
            int4v p;
            p[0] = __builtin_bit_cast(int, __builtin_amdgcn_cvt_pkrtz(w0[0], w0[1]));
            p[1] = __builtin_bit_cast(int, __builtin_amdgcn_cvt_pkrtz(w0[2], w0[3]));
            p[2] = __builtin_bit_cast(int, __builtin_amdgcn_cvt_pkrtz(w1[0], w1[1]));
            p[3] = __builtin_bit_cast(int, __builtin_amdgcn_cvt_pkrtz(w1[2], w1[3]));
            wf[ot][kc] = __builtin_bit_cast(half8_t, p);
        }
    }

    if (z < 2) {
        const float scale = (z == 0) ? LOG2E : 1.0f;
        _Float16* dstT = (z == 0) ? fT : gT;
#pragma unroll
        for (int ot = 0; ot < 2; ++ot) {
            f32x16 acc = {};
#pragma unroll
            for (int kc = 0; kc < 4; ++kc)
                acc = __builtin_amdgcn_mfma_f32_32x32x16_f16(xf[kc], wf[ot][kc], acc, 0, 0, 0);
            // D: col(lane)=o_local, row(reg)=px_local
            const float bv = bias[ot * 32 + l31];
#pragma unroll
            for (int r = 0; r < 16; ++r) {
                const int prow = (r & 3) + 8 * (r >> 2) + 4 * q5;
                const int n = n0 + wv * 32 + prow;
                dstT[(size_t)(b * NN + n) * CC + ot * 32 + l31] =
                    (_Float16)((acc[r] + bv) * scale);
            }
        }
    } else {
        _Float16* hbase = hT + ((size_t)(b * (NN / 32) + (n0 + wv * 32) / 32) * CC) * 32;
#pragma unroll
        for (int ot = 0; ot < 2; ++ot) {
            f32x16 acc = {};
#pragma unroll
            for (int kc = 0; kc < 4; ++kc)
                acc = __builtin_amdgcn_mfma_f32_32x32x16_f16(wf[ot][kc], xf[kc], acc, 0, 0, 0);
            // D: col(lane)=px_local, row(reg)=o_local
#pragma unroll
            for (int rb = 0; rb < 4; ++rb) {
                const f32x4 b4 = *(const f32x4*)(bias + ot * 32 + rb * 8 + q5 * 4);
#pragma unroll
                for (int k = 0; k < 4; ++k) {
                    const int c = ot * 32 + rb * 8 + q5 * 4 + k;
                    hbase[(size_t)c * 32 + l31] = (_Float16)(acc[rb * 4 + k] + b4[k]);
                }
            }
        }
    }
}

// ---------------------------------------------------------------------------
// Kernel B: partial row sums of exp2(logits). grid (NN/128, B, JCH), block 256.
// Wave owns i-tile 32; f A-frags entirely in registers. g streamed 64-j tiles
// through double-buffered LDS. 32x32x16 MFMA.
// ---------------------------------------------------------------------------
__global__ __launch_bounds__(256, 4) void stats_kernel(
    const _Float16* __restrict__ fT, const _Float16* __restrict__ gT,
    float* __restrict__ lpart)
{
    __shared__ _Float16 gbuf[2][64][72];   // stride 72 halves

    const int lane = threadIdx.x & 63;
    const int wv   = threadIdx.x >> 6;
    const int b    = blockIdx.y;
    const int jc   = blockIdx.z;
    const int i0   = blockIdx.x * 128 + wv * 32;
    const int l31  = lane & 31;
    const int q5   = lane >> 5;

    // A-frags (f rows i0..i0+31, K=64 in 4 chunks) — fixed in registers
    half8_t a[4];
    const _Float16* fa = fT + (size_t)(b * NN + i0 + l31) * CC + q5 * 8;
#pragma unroll
    for (int kc = 0; kc < 4; ++kc) a[kc] = *(const half8_t*)(fa + kc * 16);

    const _Float16* gchunk = gT + (size_t)(b * NN + jc * (NN / JCH)) * CC;
    const int T = NN / JCH / 64;   // 8 tiles of 64 j

    const int srow = wv * 16 + (lane >> 3);
    const int scol = (lane & 7) * 8;

    {   // stage tile 0
        const half8_t v0 = *(const half8_t*)(gchunk + (size_t)srow * CC + scol);
        const half8_t v1 = *(const half8_t*)(gchunk + (size_t)(srow + 8) * CC + scol);
        *(half8_t*)&gbuf[0][srow][scol] = v0;
        *(half8_t*)&gbuf[0][srow + 8][scol] = v1;
    }
    __syncthreads();

    float l16[16];
#pragma unroll
    for (int r = 0; r < 16; ++r) l16[r] = 0.f;

    for (int t = 0; t < T; ++t) {
        const int buf = t & 1;
        const bool pf = (t + 1 < T);
        half8_t p0, p1;
        if (pf) {
            const _Float16* src = gchunk + (size_t)((t + 1) * 64 + srow) * CC + scol;
            p0 = *(const half8_t*)(src);
            p1 = *(const half8_t*)(src + 8 * CC);
        }
#pragma unroll
        for (int js = 0; js < 2; ++js) {
            const _Float16* grow = &gbuf[buf][js * 32 + l31][0] + q5 * 8;
            f32x16 s = {};
#pragma unroll
            for (int kc = 0; kc < 4; ++kc) {
                const half8_t bfr = *(const half8_t*)(grow + kc * 16);
                s = __builtin_amdgcn_mfma_f32_32x32x16_f16(a[kc], bfr, s, 0, 0, 0);
            }
#pragma unroll
            for (int r = 0; r < 16; ++r) l16[r] += __builtin_exp2f(s[r]);
        }
        if (pf) {
            *(half8_t*)&gbuf[buf ^ 1][srow][scol] = p0;
            *(half8_t*)&gbuf[buf ^ 1][srow + 8][scol] = p1;
        }
        __syncthreads();
    }

    // reduce across the 32 j-columns (lanes sharing q5)
#pragma unroll
    for (int r = 0; r < 16; ++r) {
#pragma unroll
        for (int off = 1; off < 32; off <<= 1)
            l16[r] += __shfl_xor(l16[r], off);
    }

    if (l31 == 0) {
        float* lp = lpart + (size_t)jc * BB * NN + b * NN + i0;
#pragma unroll
        for (int rb = 0; rb < 4; ++rb) {
            // regs rb*4..rb*4+3 -> rows 8*rb + 4*q5 + 0..3
            f32x4 v;
#pragma unroll
            for (int k = 0; k < 4; ++k) v[k] = l16[rb * 4 + k];
            *(f32x4*)(lp + rb * 8 + q5 * 4) = v;
        }
    }
}

// ---------------------------------------------------------------------------
// Kernel B2: nbias = -log2(sum_jc lpart)  (softmax normalizer, log2 domain)
// ---------------------------------------------------------------------------
__global__ __launch_bounds__(256) void rmerge_kernel(
    const float* __restrict__ lpart, float* __restrict__ nbias)
{
    const int idx = blockIdx.x * 256 + threadIdx.x;
    float s = 0.f;
#pragma unroll
    for (int jc = 0; jc < JCH; ++jc) s += lpart[(size_t)jc * BB * NN + idx];
    nbias[idx] = -__builtin_log2f(s);
}

// ---------------------------------------------------------------------------
// Kernel C: partial out chunks. grid (NN/128, B, NIC), block 256.
// Wave owns j-tile 32 (g B-frags in registers); streams i in tiles of 64
// (two 32-i halves per iteration) through double-buffered LDS, ONE barrier
// per 64-i tile. P's C->B layout transform in-register via shfl_xor(32).
// Normalizer folded into S-MFMA C-init: P = exp2(s + nbias) in (0,1].
// ---------------------------------------------------------------------------
__global__ __launch_bounds__(256, 4) void attn_kernel(
    const _Float16* __restrict__ fT, const _Float16* __restrict__ gT,
    const _Float16* __restrict__ hT, const float* __restrict__ nbias,
    _Float16* __restrict__ pout)
{
    __shared__ _Float16 fbuf[2][64][72];   // 18.4 KB (i rows, 64 c + pad)
    __shared__ _Float16 hbuf[2][64][72];   // 18.4 KB (c rows, 64 i + pad)

    const int lane = threadIdx.x & 63;
    const int wv   = threadIdx.x >> 6;
    const int b    = blockIdx.y;
    const int ic   = blockIdx.z;
    const int l31  = lane & 31;
    const int q5   = lane >> 5;
    const int j    = blockIdx.x * 128 + wv * 32 + l31;

    // g B-frags fixed per wave: B[k=c][n=j], 4 K-chunks
    half8_t bg[4];
    const _Float16* grow = gT + (size_t)(b * NN + j) * CC + q5 * 8;
#pragma unroll
    for (int kc = 0; kc < 4; ++kc) bg[kc] = *(const half8_t*)(grow + kc * 16);

    f32x16 acc[2] = {};   // c 0..31, 32..63

    const int ichunk = NN / NIC;           // 1024
    const int ibase  = ic * ichunk;
    const _Float16* fchunk = fT + ((size_t)b * NN + ibase) * CC;
    const _Float16* hchunk = hT + ((size_t)(b * (NN / 32) + ibase / 32) * CC) * 32;
    const float*    nb     = nbias + b * NN + ibase;
    const int T = ichunk / 64;             // 16 iterations

    // staging maps: 256 threads cover each 8 KB (64x64 half) tile
    const int tid    = threadIdx.x;
    const int frow_s = tid >> 2;            // 0..63
    const int fcol_s = (tid & 3) * 16;      // two half8 at +0,+8
    const int hrow_s = tid >> 2;            // c 0..63
    const int hcol_s = (tid & 3) * 8;       // i within 32-chunk

    {   // stage tile 0 (f: rows=i, cols=c; h: two 32-i subtiles)
        const half8_t f0 = *(const half8_t*)(fchunk + (size_t)frow_s * CC + fcol_s);
        const half8_t f1 = *(const half8_t*)(fchunk + (size_t)frow_s * CC + fcol_s + 8);
        const half8_t h0 = *(const half8_t*)(hchunk + tid * 8);
        const half8_t h1 = *(const half8_t*)(hchunk + 2048 + tid * 8);
        *(half8_t*)&fbuf[0][frow_s][fcol_s]     = f0;
        *(half8_t*)&fbuf[0][frow_s][fcol_s + 8] = f1;
        *(half8_t*)&hbuf[0][hrow_s][hcol_s]      = h0;
        *(half8_t*)&hbuf[0][hrow_s][32 + hcol_s] = h1;
    }
    __syncthreads();

    for (int t = 0; t < T; ++t) {
        const int buf = t & 1;
        const bool pf = (t + 1 < T);
        half8_t pf0, pf1, ph0, ph1;
        if (pf) {
            const _Float16* fsrc = fchunk + (size_t)((t + 1) * 64 + frow_s) * CC + fcol_s;
            const _Float16* hsrc = hchunk + (size_t)(t + 1) * 4096 + tid * 8;
            pf0 = *(const half8_t*)(fsrc);
            pf1 = *(const half8_t*)(fsrc + 8);
            ph0 = *(const half8_t*)(hsrc);
            ph1 = *(const half8_t*)(hsrc + 2048);
        }

#pragma unroll
        for (int ih = 0; ih < 2; ++ih) {
            // ---- S = f . g^T + nbias (C-init) ----
            f32x16 s;
#pragma unroll
            for (int rb = 0; rb < 4; ++rb) {
                const f32x4 n4 = *(const f32x4*)(nb + t * 64 + ih * 32 + rb * 8 + q5 * 4);
#pragma unroll
                for (int k = 0; k < 4; ++k) s[rb * 4 + k] = n4[k];
            }
            const _Float16* frow = &fbuf[buf][ih * 32 + l31][0] + q5 * 8;
#pragma unroll
            for (int kc = 0; kc < 4; ++kc) {
                const half8_t af = *(const half8_t*)(frow + kc * 16);
                s = __builtin_amdgcn_mfma_f32_32x32x16_f16(af, bg[kc], s, 0, 0, 0);
            }

            // ---- P = exp2(s), packed f16 pairs (int-carried) ----
            int e[8];
#pragma unroll
            for (int r8 = 0; r8 < 8; ++r8) {
                e[r8] = __builtin_bit_cast(int, __builtin_amdgcn_cvt_pkrtz(
                    __builtin_exp2f(s[r8 * 2]), __builtin_exp2f(s[r8 * 2 + 1])));
            }

            // ---- C-layout -> B-layout via xor-32 lane exchange ----
            // q5=0 owns i {0-3,8-11,16-19,24-27}; q5=1 owns {4-7,...}.
            const int sA = q5 ? e[0] : e[2];
            const int sB = q5 ? e[1] : e[3];
            const int sC = q5 ? e[4] : e[6];
            const int sD = q5 ? e[5] : e[7];
            const int rA = __shfl_xor(sA, 32, 64);
            const int rB = __shfl_xor(sB, 32, 64);
            const int rC = __shfl_xor(sC, 32, 64);
            const int rD = __shfl_xor(sD, 32, 64);
            int4v b0, b1;
            b0[0] = q5 ? rA   : e[0];
            b0[1] = q5 ? rB   : e[1];
            b0[2] = q5 ? e[2] : rA;
            b0[3] = q5 ? e[3] : rB;
            b1[0] = q5 ? rC   : e[4];
            b1[1] = q5 ? rD   : e[5];
            b1[2] = q5 ? e[6] : rC;
            b1[3] = q5 ? e[7] : rD;
            const half8_t B0 = __builtin_bit_cast(half8_t, b0);
            const half8_t B1 = __builtin_bit_cast(half8_t, b1);

            // ---- PV: acc[ct] += h[ct*32+..][i] . P[i][j] ----
#pragma unroll
            for (int ct = 0; ct < 2; ++ct) {
                const half8_t ah0 = *(const half8_t*)(&hbuf[buf][ct * 32 + l31][0] + ih * 32 + q5 * 8);
                acc[ct] = __builtin_amdgcn_mfma_f32_32x32x16_f16(ah0, B0, acc[ct], 0, 0, 0);
            }
#pragma unroll
            for (int ct = 0; ct < 2; ++ct) {
                const half8_t ah1 = *(const half8_t*)(&hbuf[buf][ct * 32 + l31][0] + ih * 32 + 16 + q5 * 8);
                acc[ct] = __builtin_amdgcn_mfma_f32_32x32x16_f16(ah1, B1, acc[ct], 0, 0, 0);
            }
        }

        if (pf) {
            *(half8_t*)&fbuf[buf ^ 1][frow_s][fcol_s]     = pf0;
            *(half8_t*)&fbuf[buf ^ 1][frow_s][fcol_s + 8] = pf1;
            *(half8_t*)&hbuf[buf ^ 1][hrow_s][hcol_s]      = ph0;
            *(half8_t*)&hbuf[buf ^ 1][hrow_s][32 + hcol_s] = ph1;
        }
        __syncthreads();
    }

    // epilogue: pout[ic][b][c][j]; c = ct*32 + (r&3)+8*(r>>2)+4*q5
    _Float16* pb_out = pout + (((size_t)ic * BB + b) * CC) * NN;
#pragma unroll
    for (int ct = 0; ct < 2; ++ct) {
#pragma unroll
        for (int r = 0; r < 16; ++r) {
            const int c = ct * 32 + (r & 3) + 8 * (r >> 2) + 4 * q5;
            pb_out[(size_t)c * NN + j] = (_Float16)acc[ct][r];
        }
    }
}

// ---------------------------------------------------------------------------
// Kernel D: out = gamma * sum_ic pout[ic] + x.  8 elems/thread, vectorized.
// ---------------------------------------------------------------------------
__global__ __launch_bounds__(256) void combine_kernel(
    const float* __restrict__ x, const float* __restrict__ gammap,
    const _Float16* __restrict__ pout, float* __restrict__ out)
{
    const float gam = gammap[0];
    const size_t i8 = ((size_t)blockIdx.x * 256 + threadIdx.x) * 8;
    const size_t TOT = (size_t)BB * CC * NN;

    float s[8] = {0.f, 0.f, 0.f, 0.f, 0.f, 0.f, 0.f, 0.f};
#pragma unroll
    for (int ic = 0; ic < NIC; ++ic) {
        const half8_t p = *(const half8_t*)(pout + ic * TOT + i8);
#pragma unroll
        for (int k = 0; k < 8; ++k) s[k] += (float)p[k];
    }
    const f32x4 x0 = *(const f32x4*)(x + i8);
    const f32x4 x1 = *(const f32x4*)(x + i8 + 4);
    f32x4 o0, o1;
#pragma unroll
    for (int k = 0; k < 4; ++k) { o0[k] = gam * s[k] + x0[k]; o1[k] = gam * s[k + 4] + x1[k]; }
    *(f32x4*)(out + i8) = o0;
    *(f32x4*)(out + i8 + 4) = o1;
}

// ---------------------------------------------------------------------------
extern "C" void kernel_launch(void* const* d_in, const int* in_sizes, int n_in,
                              void* d_out, int out_size, void* d_ws, size_t ws_size,
                              hipStream_t stream) {
    const float* x     = (const float*)d_in[0];
    const float* Wf    = (const float*)d_in[1];
    const float* bf    = (const float*)d_in[2];
    const float* Wg    = (const float*)d_in[3];
    const float* bg    = (const float*)d_in[4];
    const float* Wh    = (const float*)d_in[5];
    const float* bh    = (const float*)d_in[6];
    const float* gamma = (const float*)d_in[7];
    float* out = (float*)d_out;

    const size_t TOT = (size_t)BB * CC * NN;        // 2M elems
    _Float16* fT   = (_Float16*)d_ws;               // 4 MB
    _Float16* gT   = fT + TOT;                      // 4 MB
    _Float16* hT   = gT + TOT;                      // 4 MB
    _Float16* pout = hT + TOT;                      // NIC * 4 MB
    float* lpart   = (float*)(pout + (size_t)NIC * TOT);  // 1 MB
    float* nbias   = lpart + (size_t)JCH * BB * NN;       // 128 KB

    qkv_kernel<<<dim3(NN / 128, BB, 3), 256, 0, stream>>>(
        x, Wf, bf, Wg, bg, Wh, bh, fT, gT, hT);
    stats_kernel<<<dim3(NN / 128, BB, JCH), 256, 0, stream>>>(fT, gT, lpart);
    rmerge_kernel<<<dim3(BB * NN / 256), 256, 0, stream>>>(lpart, nbias);
    attn_kernel<<<dim3(NN / 128, BB, NIC), 256, 0, stream>>>(fT, gT, hT, nbias, pout);
    combine_kernel<<<dim3(TOT / (256 * 8)), 256, 0, stream>>>(x, gamma, pout, out);
}